// Round 9
// baseline (3932.310 us; speedup 1.0000x reference)
//
#include <hip/hip_runtime.h>

#define EMB      128
#define N_NODES_ 50000
#define N_EDGES_ 800000
#define N_GRAPH_ 256
#define NLAYER_  5

// packed-weight layout offsets (ushort elements)
#define WP_ATOM  573440
#define WP_NODE0 589824
#define WP_EMB   671744
#define WP_TOTAL 675840

typedef short short8 __attribute__((ext_vector_type(8)));
typedef float floatx4 __attribute__((ext_vector_type(4)));

__device__ __forceinline__ float silu_f(float x) {
    return __fdividef(x, 1.0f + __expf(-x));
}
__device__ __forceinline__ float bf2f(unsigned short h) {
    return __uint_as_float(((unsigned)h) << 16);
}
__device__ __forceinline__ unsigned short f2bf(float f) {
    unsigned u = __float_as_uint(f);
    unsigned r = 0x7FFFu + ((u >> 16) & 1u);
    return (unsigned short)((u + r) >> 16);
}

#if defined(__has_builtin)
#if __has_builtin(__builtin_amdgcn_cvt_pk_bf16_f32)
#define HAVE_PK_BF16 1
#endif
#endif
#ifdef HAVE_PK_BF16
typedef __bf16 bf16x2 __attribute__((ext_vector_type(2)));
__device__ __forceinline__ unsigned f2bf_pk(float a, float b) {
    bf16x2 v = __builtin_amdgcn_cvt_pk_bf16_f32(a, b);
    unsigned u;
    __builtin_memcpy(&u, &v, 4);
    return u;
}
#else
__device__ __forceinline__ unsigned f2bf_pk(float a, float b) {
    return (unsigned)f2bf(a) | ((unsigned)f2bf(b) << 16);
}
#endif

// wave-local LDS ordering: same-wave DS ops are in-order on HW; the fence
// pins compiler ordering (wavefront-scope -> no waitcnt emitted).
__device__ __forceinline__ void wave_lds_fence() {
    __builtin_amdgcn_fence(__ATOMIC_ACQ_REL, "wavefront");
    __builtin_amdgcn_wave_barrier();
}

// ---------------------------------------------------------------------------
// Edge sort by destination row: histogram -> 1-block scan -> atomic scatter.
// ---------------------------------------------------------------------------
__global__ __launch_bounds__(256) void hist_kernel(
    const int* __restrict__ row, int* __restrict__ hist)
{
    const int e = blockIdx.x * 256 + threadIdx.x;
    if (e < N_EDGES_) atomicAdd(&hist[row[e]], 1);
}

__global__ __launch_bounds__(256) void scan_kernel(
    const int* __restrict__ hist, int* __restrict__ cursor)
{
    __shared__ int ssum[256];
    const int tid = threadIdx.x;
    const int chunk = (N_NODES_ + 255) / 256;
    const int base = tid * chunk;
    int s = 0;
    for (int i = 0; i < chunk; ++i) {
        const int idx = base + i;
        if (idx < N_NODES_) s += hist[idx];
    }
    ssum[tid] = s;
    __syncthreads();
    for (int off = 1; off < 256; off <<= 1) {
        const int t2 = (tid >= off) ? ssum[tid - off] : 0;
        __syncthreads();
        ssum[tid] += t2;
        __syncthreads();
    }
    int run = ssum[tid] - s;
    for (int i = 0; i < chunk; ++i) {
        const int idx = base + i;
        if (idx < N_NODES_) { cursor[idx] = run; run += hist[idx]; }
    }
}

__global__ __launch_bounds__(256) void scatter_kernel(
    const int* __restrict__ row, const int* __restrict__ col,
    int* __restrict__ cursor, int* __restrict__ row_s, int* __restrict__ col_s)
{
    const int e = blockIdx.x * 256 + threadIdx.x;
    if (e >= N_EDGES_) return;
    const int r = row[e];
    const int p = atomicAdd(&cursor[r], 1);
    row_s[p] = r;
    col_s[p] = col[e];
}

// ---------------------------------------------------------------------------
// Weight packing: fp32 [K][128] -> bf16 A-operand (W^T) fragment order.
// 256 blocks: 0..199 edge MLP | 200..207 atom_w | 208..247 node_w | 248..255 emb
// ---------------------------------------------------------------------------
__global__ __launch_bounds__(256) void pack_w_kernel(
    const float* __restrict__ edge_w0, const float* __restrict__ edge_w,
    const float* __restrict__ atom_w, const float* __restrict__ node_w,
    const float* __restrict__ edge_emb_w,
    unsigned short* __restrict__ Wp)
{
    const int bid = blockIdx.x;
    int Kb, t;
    const float* src;
    unsigned short* dst;
    if (bid < 200) {
        const int l = bid / 40, r = bid % 40, s = r / 8;
        t = r % 8;
        Kb = (s == 0) ? 12 : 4;
        src = (s == 0) ? edge_w0 + (size_t)l * 384 * 128
                       : edge_w + ((size_t)l * 4 + (s - 1)) * 128 * 128;
        dst = Wp + (size_t)l * 114688 + ((s == 0) ? 0 : (49152 + (s - 1) * 16384))
            + (size_t)t * Kb * 512;
    } else if (bid < 208) {
        t = bid - 200; Kb = 4; src = atom_w;
        dst = Wp + WP_ATOM + (size_t)t * Kb * 512;
    } else if (bid < 248) {
        const int l = (bid - 208) >> 3; t = (bid - 208) & 7; Kb = 4;
        src = node_w + (size_t)l * 128 * 128;
        dst = Wp + WP_NODE0 + (size_t)l * 16384 + (size_t)t * Kb * 512;
    } else {
        t = bid - 248; Kb = 1; src = edge_emb_w;
        dst = Wp + WP_EMB + (size_t)t * 512;
    }
    const int n = Kb * 512;
    for (int p = threadIdx.x; p < n; p += 256) {
        const int j = p & 7, lane = (p >> 3) & 63, kb = p >> 9;
        const int k  = kb * 32 + ((lane >> 4) << 3) + j;
        const int nn = t * 16 + (lane & 15);
        dst[p] = f2bf(src[(size_t)k * 128 + nn]);
    }
}

// ---------------------------------------------------------------------------
// WAVE-PRIVATE sorted-edge MFMA edge MLP. Each wave owns 16 edges (its own 16
// LDS rows) and computes all 8 n-tiles -> zero block barriers through the 5
// stages (waves slip; silu of one wave overlaps MFMA of another). One
// __syncthreads before the cross-wave aggregation epilogue.
// ---------------------------------------------------------------------------
__global__ __launch_bounds__(256, 3) void edge_mlp_wp_kernel(
    const unsigned short* __restrict__ h_node_bf, unsigned short* __restrict__ h_edge,
    float* __restrict__ agg,
    const int* __restrict__ row_s, const int* __restrict__ col_s,
    const unsigned short* __restrict__ Wp,
    const float* __restrict__ b0, const float* __restrict__ bh)
{
    __shared__ __align__(16) unsigned short A[64][392];   // 50,176 B
    __shared__ int rv[64];
    const int tid  = threadIdx.x;
    const int lane = tid & 63;
    const int wv   = tid >> 6;
    const int e0   = blockIdx.x * 64;

    // phase-2 row table (consumed only after the __syncthreads below)
    if (lane < 16) rv[wv * 16 + lane] = row_s[e0 + wv * 16 + lane];

    // wave-private staging: t = own edge row (t = wv*16 + (lane>>2))
    {
        const int t = tid >> 2, q = tid & 3;
        const int rg = row_s[e0 + t];
        const int cg = col_s[e0 + t];
        const unsigned short* pe = &h_edge[(size_t)(e0 + t) * 128];
        const unsigned short* pr = &h_node_bf[(size_t)rg * 128];
        const unsigned short* pc = &h_node_bf[(size_t)cg * 128];
#pragma unroll
        for (int i = 0; i < 12; ++i) {
            const int ch = q + 4 * i;
            const int k8 = ch << 3;
            const unsigned short* src = (ch < 16) ? (pe + k8)
                                      : (ch < 32) ? (pr + (k8 - 128))
                                                  : (pc + (k8 - 256));
            *(short8*)&A[t][k8] = *(const short8*)src;
        }
    }
    wave_lds_fence();

    const int lr = lane & 15;
    const int lg = lane >> 4;
    unsigned short* myrow = &A[wv * 16 + lr][0];

    for (int s = 0; s < 5; ++s) {
        const int Kb = (s == 0) ? 12 : 4;
        const unsigned short* __restrict__ Ws =
            Wp + ((s == 0) ? 0 : (49152 + (s - 1) * 16384));
        const float* __restrict__ bias = (s == 0) ? b0 : (bh + (s - 1) * 128);

        floatx4 acc[8];
#pragma unroll
        for (int nt = 0; nt < 8; ++nt) {
            const float4 bv = *(const float4*)&bias[nt * 16 + lg * 4];
            acc[nt] = (floatx4){bv.x, bv.y, bv.z, bv.w};
        }
#pragma unroll 2
        for (int kb = 0; kb < Kb; ++kb) {
            const short8 mf = *(const short8*)(myrow + kb * 32 + lg * 8);
#pragma unroll
            for (int nt = 0; nt < 8; ++nt) {
                const short8 wf = *(const short8*)(Ws + ((size_t)(nt * Kb + kb) * 64 + lane) * 8);
                acc[nt] = __builtin_amdgcn_mfma_f32_16x16x32_bf16(wf, mf, acc[nt], 0, 0, 0);
            }
        }
        wave_lds_fence();    // own-wave reads complete before overwrite
#pragma unroll
        for (int nt = 0; nt < 8; ++nt) {
            uint2 p;
            p.x = f2bf_pk(silu_f(acc[nt][0]), silu_f(acc[nt][1]));
            p.y = f2bf_pk(silu_f(acc[nt][2]), silu_f(acc[nt][3]));
            *(uint2*)(myrow + nt * 16 + lg * 4) = p;
        }
        wave_lds_fence();    // writes visible to own wave's next-stage reads
    }

    // phase 1 (wave-private rows): h_edge_new = old + m; global + LDS
    {
        const int t = tid >> 2, q = tid & 3;
        unsigned short* pe = &h_edge[(size_t)(e0 + t) * 128];
#pragma unroll
        for (int i = 0; i < 4; ++i) {
            const int k8 = (q + 4 * i) << 3;
            const short8 mv = *(const short8*)&A[t][k8];
            const short8 ov = *(const short8*)(pe + k8);
            float he[8];
#pragma unroll
            for (int j = 0; j < 8; ++j)
                he[j] = bf2f((unsigned short)ov[j]) + bf2f((unsigned short)mv[j]);
            uint4 sv;
            sv.x = f2bf_pk(he[0], he[1]);
            sv.y = f2bf_pk(he[2], he[3]);
            sv.z = f2bf_pk(he[4], he[5]);
            sv.w = f2bf_pk(he[6], he[7]);
            *(uint4*)(pe + k8) = sv;
            *(uint4*)&A[t][k8] = sv;
        }
    }
    __syncthreads();   // the single block barrier: phase 2 reads across waves

    // phase 2: run-length merged scatter atomics (lane-consecutive flushes)
    {
        const int c    = tid & 127;
        const int half = tid >> 7;
        const int tstart = half * 32;
        int curRow = rv[tstart];
        float accv = 0.f;
#pragma unroll 8
        for (int t = tstart; t < tstart + 32; ++t) {
            const int rr = rv[t];
            const float v = bf2f(A[t][c]);
            if (rr != curRow) {
                atomicAdd(&agg[(size_t)curRow * 128 + c], accv);
                accv = 0.f;
                curRow = rr;
            }
            accv += v;
        }
        atomicAdd(&agg[(size_t)curRow * 128 + c], accv);
    }
}

// ---------------------------------------------------------------------------
// MFMA row GEMM: [N,128] @ [128,128] + bias (packed weights), optional
// gather (fp32 src rows) / silu / bf16 residual. 64 rows/block, wave-private.
// ---------------------------------------------------------------------------
template <int GATHER, int RESID, int SILU>
__global__ __launch_bounds__(256, 4) void row_gemm_mfma_kernel(
    const float* __restrict__ src, const int* __restrict__ gidx,
    const unsigned short* __restrict__ Wpm, const float* __restrict__ bias,
    unsigned short* __restrict__ dst, int N)
{
    __shared__ __align__(16) unsigned short B[64][136];
    const int tid  = threadIdx.x;
    const int lane = tid & 63;
    const int wv   = tid >> 6;
    const int n0   = blockIdx.x * 64;

    {
        const int t = tid >> 2, q = tid & 3;
        const int node = n0 + t;
        const float* srow = src;
        if (node < N) {
            const int rr = GATHER ? gidx[node] : node;
            srow = &src[(size_t)rr * 128];
        }
#pragma unroll
        for (int i = 0; i < 4; ++i) {
            const int k8 = (q + 4 * i) << 3;
            uint4 pk = make_uint4(0, 0, 0, 0);
            if (node < N) {
                const float4 f0 = *(const float4*)(srow + k8);
                const float4 f1 = *(const float4*)(srow + k8 + 4);
                pk.x = f2bf_pk(f0.x, f0.y);
                pk.y = f2bf_pk(f0.z, f0.w);
                pk.z = f2bf_pk(f1.x, f1.y);
                pk.w = f2bf_pk(f1.z, f1.w);
            }
            *(uint4*)&B[t][k8] = pk;
        }
    }
    wave_lds_fence();

    const int lr = lane & 15, lg = lane >> 4;
    floatx4 acc[8];
#pragma unroll
    for (int nt = 0; nt < 8; ++nt) {
        const float4 bv = *(const float4*)&bias[nt * 16 + lg * 4];
        acc[nt] = (floatx4){bv.x, bv.y, bv.z, bv.w};
    }
    const unsigned short* brow = &B[wv * 16 + lr][0];
#pragma unroll 2
    for (int kb = 0; kb < 4; ++kb) {
        const short8 mf = *(const short8*)(brow + kb * 32 + lg * 8);
#pragma unroll
        for (int nt = 0; nt < 8; ++nt) {
            const short8 wf = *(const short8*)(Wpm + ((size_t)(nt * 4 + kb) * 64 + lane) * 8);
            acc[nt] = __builtin_amdgcn_mfma_f32_16x16x32_bf16(wf, mf, acc[nt], 0, 0, 0);
        }
    }
    const int node = n0 + wv * 16 + lr;
    if (node < N) {
        unsigned short* drow = &dst[(size_t)node * 128];
#pragma unroll
        for (int nt = 0; nt < 8; ++nt) {
            float x0 = acc[nt][0], x1 = acc[nt][1], x2 = acc[nt][2], x3 = acc[nt][3];
            if (SILU) { x0 = silu_f(x0); x1 = silu_f(x1); x2 = silu_f(x2); x3 = silu_f(x3); }
            unsigned short* p = drow + nt * 16 + lg * 4;
            if (RESID) {
                const uint2 d = *(const uint2*)p;
                x0 += bf2f((unsigned short)(d.x & 0xFFFF));
                x1 += bf2f((unsigned short)(d.x >> 16));
                x2 += bf2f((unsigned short)(d.y & 0xFFFF));
                x3 += bf2f((unsigned short)(d.y >> 16));
            }
            uint2 o;
            o.x = f2bf_pk(x0, x1);
            o.y = f2bf_pk(x2, x3);
            *(uint2*)p = o;
        }
    }
}

// ---------------------------------------------------------------------------
// MFMA edge embedding: basis [64,32] bf16 in LDS, one K=32 MFMA pass.
// ---------------------------------------------------------------------------
__global__ __launch_bounds__(256, 4) void edge_embed_mfma_kernel(
    const float* __restrict__ pos, const int* __restrict__ row, const int* __restrict__ col,
    const unsigned short* __restrict__ Wpe, const float* __restrict__ bemb,
    unsigned short* __restrict__ h_edge)
{
    __shared__ __align__(16) unsigned short Bas[64][40];
    const int tid  = threadIdx.x;
    const int lane = tid & 63;
    const int wv   = tid >> 6;
    const int e0   = blockIdx.x * 64;

    {
        const int t = tid >> 2, q = tid & 3;
        const int rr = row[e0 + t], cc = col[e0 + t];
        const float dx = pos[rr * 3 + 0] - pos[cc * 3 + 0];
        const float dy = pos[rr * 3 + 1] - pos[cc * 3 + 1];
        const float dz = pos[rr * 3 + 2] - pos[cc * 3 + 2];
        const float d = sqrtf(dx * dx + dy * dy + dz * dz);
        const float invs = 32.0f / 5.0f;
        float e[8];
#pragma unroll
        for (int j = 0; j < 8; ++j) {
            const float mu = (float)(q * 8 + j) * (5.0f / 31.0f);
            const float tt = (d - mu) * invs;
            e[j] = __expf(-0.5f * tt * tt);
        }
        uint4 pk;
        pk.x = f2bf_pk(e[0], e[1]);
        pk.y = f2bf_pk(e[2], e[3]);
        pk.z = f2bf_pk(e[4], e[5]);
        pk.w = f2bf_pk(e[6], e[7]);
        *(uint4*)&Bas[t][q * 8] = pk;
    }
    wave_lds_fence();

    const int lr = lane & 15, lg = lane >> 4;
    floatx4 acc[8];
#pragma unroll
    for (int nt = 0; nt < 8; ++nt) {
        const float4 bv = *(const float4*)&bemb[nt * 16 + lg * 4];
        acc[nt] = (floatx4){bv.x, bv.y, bv.z, bv.w};
    }
    const short8 mf = *(const short8*)&Bas[wv * 16 + lr][lg * 8];
#pragma unroll
    for (int nt = 0; nt < 8; ++nt) {
        const short8 wf = *(const short8*)(Wpe + ((size_t)nt * 64 + lane) * 8);
        acc[nt] = __builtin_amdgcn_mfma_f32_16x16x32_bf16(wf, mf, acc[nt], 0, 0, 0);
    }
    unsigned short* erow = &h_edge[(size_t)(e0 + wv * 16 + lr) * 128];
#pragma unroll
    for (int nt = 0; nt < 8; ++nt) {
        uint2 o;
        o.x = f2bf_pk(acc[nt][0], acc[nt][1]);
        o.y = f2bf_pk(acc[nt][2], acc[nt][3]);
        *(uint2*)(erow + nt * 16 + lg * 4) = o;
    }
}

// ---------------------------------------------------------------------------
// Graph pooling (bf16 node state) + output head.
// ---------------------------------------------------------------------------
__global__ __launch_bounds__(128) void pool_kernel(
    const unsigned short* __restrict__ h_node_bf, const int* __restrict__ batch,
    float* __restrict__ sums, float* __restrict__ cnt, int N)
{
    __shared__ int bb[256];
    const int tid = threadIdx.x;
    const int n0 = blockIdx.x * 256;
    for (int idx = tid; idx < 256; idx += 128) {
        int n = n0 + idx;
        bb[idx] = (n < N) ? batch[n] : -1;
    }
    __syncthreads();
    int cur = bb[0];
    float run = 0.f, runc = 0.f;
    for (int i = 0; i < 256; ++i) {
        const int b = bb[i];
        if (b < 0) break;
        if (b != cur) {
            atomicAdd(&sums[(size_t)cur * 128 + tid], run);
            if (tid == 0) atomicAdd(&cnt[cur], runc);
            run = 0.f; runc = 0.f; cur = b;
        }
        run += bf2f(h_node_bf[(size_t)(n0 + i) * 128 + tid]);
        runc += 1.f;
    }
    atomicAdd(&sums[(size_t)cur * 128 + tid], run);
    if (tid == 0) atomicAdd(&cnt[cur], runc);
}

__global__ __launch_bounds__(256) void final_kernel(
    const float* __restrict__ sums, const float* __restrict__ cnt,
    const float* __restrict__ out_w, const float* __restrict__ out_b,
    float* __restrict__ out)
{
    const int g = threadIdx.x;
    const float c = fmaxf(cnt[g], 1.0f);
    float acc = 0.f;
    for (int jj = 0; jj < 128; ++jj) acc = fmaf(sums[(size_t)g * 128 + jj], out_w[jj], acc);
    out[g] = acc / c + out_b[0];
}

__global__ void zero_out_kernel(float* out, int n) {
    int i = blockIdx.x * 256 + threadIdx.x;
    if (i < n) out[i] = 0.f;
}

// ---------------------------------------------------------------------------

extern "C" void kernel_launch(void* const* d_in, const int* in_sizes, int n_in,
                              void* d_out, int out_size, void* d_ws, size_t ws_size,
                              hipStream_t stream)
{
    const int*   z          = (const int*)  d_in[0];
    const float* pos        = (const float*)d_in[1];
    const int*   batch      = (const int*)  d_in[2];
    const int*   eidx       = (const int*)  d_in[3];
    const float* atom_table = (const float*)d_in[4];
    const float* atom_w     = (const float*)d_in[5];
    const float* atom_b     = (const float*)d_in[6];
    const float* edge_emb_w = (const float*)d_in[7];
    const float* edge_emb_b = (const float*)d_in[8];
    const float* edge_w0    = (const float*)d_in[9];
    const float* edge_b0    = (const float*)d_in[10];
    const float* edge_w     = (const float*)d_in[11];
    const float* edge_b     = (const float*)d_in[12];
    const float* node_w     = (const float*)d_in[13];
    const float* node_b     = (const float*)d_in[14];
    const float* out_w      = (const float*)d_in[15];
    const float* out_b      = (const float*)d_in[16];
    const int* row = eidx;
    const int* col = eidx + N_EDGES_;

    // ws layout (~251.5 MB; ws known >= 257.3 MB from rounds 4-6):
    // agg f32 | sums f32 | cnt f32 | h_node bf16 | h_edge bf16 | Wp bf16 |
    // hist | cursor | row_s | col_s
    float* aggb = (float*)d_ws;
    float* sums = aggb + (size_t)N_NODES_ * EMB;
    float* cnt  = sums + (size_t)N_GRAPH_ * EMB;
    unsigned short* h_node_bf = (unsigned short*)(cnt + N_GRAPH_);
    unsigned short* h_edge    = h_node_bf + (size_t)N_NODES_ * EMB;
    unsigned short* Wp        = h_edge + (size_t)N_EDGES_ * EMB;
    int* hist   = (int*)(Wp + WP_TOTAL);
    int* cursor = hist + N_NODES_;
    int* row_s  = cursor + N_NODES_;
    int* col_s  = row_s + N_EDGES_;

    const size_t need = ((size_t)(N_NODES_ * EMB + N_GRAPH_ * EMB + N_GRAPH_)) * 4
                      + ((size_t)N_NODES_ * EMB + (size_t)N_EDGES_ * EMB + (size_t)WP_TOTAL) * 2
                      + ((size_t)N_NODES_ * 2 + (size_t)N_EDGES_ * 2) * 4;

    if (ws_size < need) {
        zero_out_kernel<<<1, 256, 0, stream>>>((float*)d_out, N_GRAPH_);
        return;
    }

    const int grid_rows64 = (N_NODES_ + 63) / 64;   // 782

    (void)hipMemsetAsync(hist, 0, N_NODES_ * sizeof(int), stream);
    hist_kernel<<<(N_EDGES_ + 255) / 256, 256, 0, stream>>>(row, hist);
    scan_kernel<<<1, 256, 0, stream>>>(hist, cursor);
    scatter_kernel<<<(N_EDGES_ + 255) / 256, 256, 0, stream>>>(row, col, cursor, row_s, col_s);

    pack_w_kernel<<<256, 256, 0, stream>>>(edge_w0, edge_w, atom_w, node_w, edge_emb_w, Wp);

    // h_node = atom_table[z] @ atom_w + atom_b
    row_gemm_mfma_kernel<1, 0, 0><<<grid_rows64, 256, 0, stream>>>(
        atom_table, z, Wp + WP_ATOM, atom_b, h_node_bf, N_NODES_);
    // h_edge = gauss(d) @ edge_emb_w + edge_emb_b
    edge_embed_mfma_kernel<<<N_EDGES_ / 64, 256, 0, stream>>>(
        pos, row_s, col_s, Wp + WP_EMB, edge_emb_b, h_edge);

    for (int l = 0; l < NLAYER_; ++l) {
        (void)hipMemsetAsync(aggb, 0, (size_t)N_NODES_ * EMB * sizeof(float), stream);
        edge_mlp_wp_kernel<<<N_EDGES_ / 64, 256, 0, stream>>>(
            h_node_bf, h_edge, aggb, row_s, col_s,
            Wp + (size_t)l * 114688,
            edge_b0 + (size_t)l * 128, edge_b + (size_t)l * 4 * 128);
        row_gemm_mfma_kernel<0, 1, 1><<<grid_rows64, 256, 0, stream>>>(
            aggb, nullptr, Wp + WP_NODE0 + (size_t)l * 16384, node_b + (size_t)l * 128,
            h_node_bf, N_NODES_);
    }

    (void)hipMemsetAsync(sums, 0, ((size_t)N_GRAPH_ * EMB + N_GRAPH_) * sizeof(float), stream);
    pool_kernel<<<(N_NODES_ + 255) / 256, 128, 0, stream>>>(h_node_bf, batch, sums, cnt, N_NODES_);
    final_kernel<<<1, 256, 0, stream>>>(sums, cnt, out_w, out_b, (float*)d_out);
}

// Round 10
// 2540.606 us; speedup vs baseline: 1.5478x; 1.5478x over previous
//
#include <hip/hip_runtime.h>

#define EMB      128
#define N_NODES_ 50000
#define N_EDGES_ 800000
#define N_GRAPH_ 256
#define NLAYER_  5

// packed-weight layout offsets (ushort elements)
#define WP_ATOM  573440
#define WP_NODE0 589824
#define WP_EMB   671744
#define WP_TOTAL 675840

typedef short short8 __attribute__((ext_vector_type(8)));
typedef float floatx4 __attribute__((ext_vector_type(4)));

__device__ __forceinline__ float silu_f(float x) {
    return __fdividef(x, 1.0f + __expf(-x));
}
__device__ __forceinline__ float bf2f(unsigned short h) {
    return __uint_as_float(((unsigned)h) << 16);
}
__device__ __forceinline__ unsigned short f2bf(float f) {
    unsigned u = __float_as_uint(f);
    unsigned r = 0x7FFFu + ((u >> 16) & 1u);
    return (unsigned short)((u + r) >> 16);
}

#if defined(__has_builtin)
#if __has_builtin(__builtin_amdgcn_cvt_pk_bf16_f32)
#define HAVE_PK_BF16 1
#endif
#endif
#ifdef HAVE_PK_BF16
typedef __bf16 bf16x2 __attribute__((ext_vector_type(2)));
__device__ __forceinline__ unsigned f2bf_pk(float a, float b) {
    bf16x2 v = __builtin_amdgcn_cvt_pk_bf16_f32(a, b);
    unsigned u;
    __builtin_memcpy(&u, &v, 4);
    return u;
}
#else
__device__ __forceinline__ unsigned f2bf_pk(float a, float b) {
    return (unsigned)f2bf(a) | ((unsigned)f2bf(b) << 16);
}
#endif

// wave-local LDS ordering (validated round 9: correctness held)
__device__ __forceinline__ void wave_lds_fence() {
    __builtin_amdgcn_fence(__ATOMIC_ACQ_REL, "wavefront");
    __builtin_amdgcn_wave_barrier();
}

// ---------------------------------------------------------------------------
// Edge sort by destination row: histogram -> 1-block scan -> atomic scatter.
// After scatter: cursor[n] = END offset of node n's edge run; hist[n] = degree.
// ---------------------------------------------------------------------------
__global__ __launch_bounds__(256) void hist_kernel(
    const int* __restrict__ row, int* __restrict__ hist)
{
    const int e = blockIdx.x * 256 + threadIdx.x;
    if (e < N_EDGES_) atomicAdd(&hist[row[e]], 1);
}

__global__ __launch_bounds__(256) void scan_kernel(
    const int* __restrict__ hist, int* __restrict__ cursor)
{
    __shared__ int ssum[256];
    const int tid = threadIdx.x;
    const int chunk = (N_NODES_ + 255) / 256;
    const int base = tid * chunk;
    int s = 0;
    for (int i = 0; i < chunk; ++i) {
        const int idx = base + i;
        if (idx < N_NODES_) s += hist[idx];
    }
    ssum[tid] = s;
    __syncthreads();
    for (int off = 1; off < 256; off <<= 1) {
        const int t2 = (tid >= off) ? ssum[tid - off] : 0;
        __syncthreads();
        ssum[tid] += t2;
        __syncthreads();
    }
    int run = ssum[tid] - s;
    for (int i = 0; i < chunk; ++i) {
        const int idx = base + i;
        if (idx < N_NODES_) { cursor[idx] = run; run += hist[idx]; }
    }
}

__global__ __launch_bounds__(256) void scatter_kernel(
    const int* __restrict__ row, const int* __restrict__ col,
    int* __restrict__ cursor, int* __restrict__ row_s, int* __restrict__ col_s)
{
    const int e = blockIdx.x * 256 + threadIdx.x;
    if (e >= N_EDGES_) return;
    const int r = row[e];
    const int p = atomicAdd(&cursor[r], 1);
    row_s[p] = r;
    col_s[p] = col[e];
}

// ---------------------------------------------------------------------------
// Weight packing: fp32 [K][128] -> bf16 A-operand (W^T) fragment order.
// 256 blocks: 0..199 edge MLP | 200..207 atom_w | 208..247 node_w | 248..255 emb
// ---------------------------------------------------------------------------
__global__ __launch_bounds__(256) void pack_w_kernel(
    const float* __restrict__ edge_w0, const float* __restrict__ edge_w,
    const float* __restrict__ atom_w, const float* __restrict__ node_w,
    const float* __restrict__ edge_emb_w,
    unsigned short* __restrict__ Wp)
{
    const int bid = blockIdx.x;
    int Kb, t;
    const float* src;
    unsigned short* dst;
    if (bid < 200) {
        const int l = bid / 40, r = bid % 40, s = r / 8;
        t = r % 8;
        Kb = (s == 0) ? 12 : 4;
        src = (s == 0) ? edge_w0 + (size_t)l * 384 * 128
                       : edge_w + ((size_t)l * 4 + (s - 1)) * 128 * 128;
        dst = Wp + (size_t)l * 114688 + ((s == 0) ? 0 : (49152 + (s - 1) * 16384))
            + (size_t)t * Kb * 512;
    } else if (bid < 208) {
        t = bid - 200; Kb = 4; src = atom_w;
        dst = Wp + WP_ATOM + (size_t)t * Kb * 512;
    } else if (bid < 248) {
        const int l = (bid - 208) >> 3; t = (bid - 208) & 7; Kb = 4;
        src = node_w + (size_t)l * 128 * 128;
        dst = Wp + WP_NODE0 + (size_t)l * 16384 + (size_t)t * Kb * 512;
    } else {
        t = bid - 248; Kb = 1; src = edge_emb_w;
        dst = Wp + WP_EMB + (size_t)t * 512;
    }
    const int n = Kb * 512;
    for (int p = threadIdx.x; p < n; p += 256) {
        const int j = p & 7, lane = (p >> 3) & 63, kb = p >> 9;
        const int k  = kb * 32 + ((lane >> 4) << 3) + j;
        const int nn = t * 16 + (lane & 15);
        dst[p] = f2bf(src[(size_t)k * 128 + nn]);
    }
}

// ---------------------------------------------------------------------------
// Sorted-edge MFMA edge MLP, round-8 structure (shared A, wave owns 2 n-tiles
// x 4 edge-tiles: weight frags amortized 4x — round 9 showed 1x reuse goes
// vmem-latency-bound). NO aggregation phase: consumer-side CSR segment sum
// happens in node_agg_gemm_kernel. Writes only h_edge_new.
// ---------------------------------------------------------------------------
__global__ __launch_bounds__(256, 3) void edge_mlp_csr_kernel(
    const unsigned short* __restrict__ h_node_bf, unsigned short* __restrict__ h_edge,
    const int* __restrict__ row_s, const int* __restrict__ col_s,
    const unsigned short* __restrict__ Wp,
    const float* __restrict__ b0, const float* __restrict__ bh)
{
    __shared__ __align__(16) unsigned short A[64][392];   // 50,176 B
    const int tid = threadIdx.x;
    const int e0 = blockIdx.x * 64;

    // staging: thread owns row t = tid>>2, chunks (tid&3)+4i
    {
        const int t = tid >> 2, q = tid & 3;
        const int rg = row_s[e0 + t];
        const int cg = col_s[e0 + t];
        const unsigned short* pe = &h_edge[(size_t)(e0 + t) * 128];
        const unsigned short* pr = &h_node_bf[(size_t)rg * 128];
        const unsigned short* pc = &h_node_bf[(size_t)cg * 128];
#pragma unroll
        for (int i = 0; i < 12; ++i) {
            const int ch = q + 4 * i;
            const int k8 = ch << 3;
            const unsigned short* src = (ch < 16) ? (pe + k8)
                                      : (ch < 32) ? (pr + (k8 - 128))
                                                  : (pc + (k8 - 256));
            *(short8*)&A[t][k8] = *(const short8*)src;
        }
    }
    __syncthreads();

    const int lane = tid & 63;
    const int wv   = tid >> 6;
    const int lr   = lane & 15;
    const int lg   = lane >> 4;
    const int nt0  = 2 * wv, nt1 = nt0 + 1;

    for (int s = 0; s < 5; ++s) {
        const int Kb = (s == 0) ? 12 : 4;
        const unsigned short* __restrict__ Ws =
            Wp + ((s == 0) ? 0 : (49152 + (s - 1) * 16384));
        const float* __restrict__ bias = (s == 0) ? b0 : (bh + (s - 1) * 128);

        const float4 bv0 = *(const float4*)&bias[nt0 * 16 + lg * 4];
        const float4 bv1 = *(const float4*)&bias[nt1 * 16 + lg * 4];
        floatx4 acc0[4], acc1[4];
#pragma unroll
        for (int et = 0; et < 4; ++et) {
            acc0[et] = (floatx4){bv0.x, bv0.y, bv0.z, bv0.w};
            acc1[et] = (floatx4){bv1.x, bv1.y, bv1.z, bv1.w};
        }

        const unsigned short* aptr0 = Ws + ((size_t)(nt0 * Kb) * 64 + lane) * 8;
        const unsigned short* aptr1 = Ws + ((size_t)(nt1 * Kb) * 64 + lane) * 8;
#pragma unroll 2
        for (int kb = 0; kb < Kb; ++kb) {
            const short8 wf0 = *(const short8*)(aptr0 + (size_t)kb * 512);
            const short8 wf1 = *(const short8*)(aptr1 + (size_t)kb * 512);
#pragma unroll
            for (int et = 0; et < 4; ++et) {
                const short8 mf = *(const short8*)&A[et * 16 + lr][kb * 32 + lg * 8];
                acc0[et] = __builtin_amdgcn_mfma_f32_16x16x32_bf16(wf0, mf, acc0[et], 0, 0, 0);
                acc1[et] = __builtin_amdgcn_mfma_f32_16x16x32_bf16(wf1, mf, acc1[et], 0, 0, 0);
            }
        }
        __syncthreads();   // all reads of A for this stage done
#pragma unroll
        for (int et = 0; et < 4; ++et) {
            uint2 p0, p1;
            p0.x = f2bf_pk(silu_f(acc0[et][0]), silu_f(acc0[et][1]));
            p0.y = f2bf_pk(silu_f(acc0[et][2]), silu_f(acc0[et][3]));
            p1.x = f2bf_pk(silu_f(acc1[et][0]), silu_f(acc1[et][1]));
            p1.y = f2bf_pk(silu_f(acc1[et][2]), silu_f(acc1[et][3]));
            *(uint2*)&A[et * 16 + lr][nt0 * 16 + lg * 4] = p0;
            *(uint2*)&A[et * 16 + lr][nt1 * 16 + lg * 4] = p1;
        }
        __syncthreads();
    }

    // epilogue: h_edge_new = old + m -> global only (no agg, no LDS writeback)
    {
        const int t = tid >> 2, q = tid & 3;
        unsigned short* pe = &h_edge[(size_t)(e0 + t) * 128];
#pragma unroll
        for (int i = 0; i < 4; ++i) {
            const int k8 = (q + 4 * i) << 3;
            const short8 mv = *(const short8*)&A[t][k8];
            const short8 ov = *(const short8*)(pe + k8);
            float he[8];
#pragma unroll
            for (int j = 0; j < 8; ++j)
                he[j] = bf2f((unsigned short)ov[j]) + bf2f((unsigned short)mv[j]);
            uint4 sv;
            sv.x = f2bf_pk(he[0], he[1]);
            sv.y = f2bf_pk(he[2], he[3]);
            sv.z = f2bf_pk(he[4], he[5]);
            sv.w = f2bf_pk(he[6], he[7]);
            *(uint4*)(pe + k8) = sv;
        }
    }
}

// ---------------------------------------------------------------------------
// Fused CSR segment-sum + MFMA node update:
//   agg[n] = sum of h_edge rows in [cursor[n]-hist[n], cursor[n])  (fp32)
//   h_node[n] += silu(agg @ node_w + node_b)
// 64 nodes/block; wave-private LDS; no atomics, no agg buffer, no memset.
// ---------------------------------------------------------------------------
__global__ __launch_bounds__(256, 4) void node_agg_gemm_kernel(
    const unsigned short* __restrict__ h_edge,
    const int* __restrict__ hist, const int* __restrict__ cur_end,
    const unsigned short* __restrict__ Wpm, const float* __restrict__ bias,
    unsigned short* __restrict__ h_node_bf, int N)
{
    __shared__ __align__(16) unsigned short B[64][136];
    const int tid  = threadIdx.x;
    const int lane = tid & 63;
    const int wv   = tid >> 6;
    const int n0   = blockIdx.x * 64;

    // segment sum: thread (t = node-in-block, q = dim quarter of 32)
    {
        const int t = tid >> 2, q = tid & 3;
        const int n = n0 + t;
        float a[32];
#pragma unroll
        for (int j = 0; j < 32; ++j) a[j] = 0.f;
        if (n < N) {
            const int e_end = cur_end[n];
            const int e_beg = e_end - hist[n];
            for (int e = e_beg; e < e_end; ++e) {
                const unsigned short* p = &h_edge[(size_t)e * 128 + q * 32];
#pragma unroll
                for (int g = 0; g < 4; ++g) {
                    const short8 v = *(const short8*)(p + g * 8);
#pragma unroll
                    for (int j = 0; j < 8; ++j)
                        a[g * 8 + j] += bf2f((unsigned short)v[j]);
                }
            }
        }
#pragma unroll
        for (int g = 0; g < 4; ++g) {
            uint4 pk;
            pk.x = f2bf_pk(a[g * 8 + 0], a[g * 8 + 1]);
            pk.y = f2bf_pk(a[g * 8 + 2], a[g * 8 + 3]);
            pk.z = f2bf_pk(a[g * 8 + 4], a[g * 8 + 5]);
            pk.w = f2bf_pk(a[g * 8 + 6], a[g * 8 + 7]);
            *(uint4*)&B[t][q * 32 + g * 8] = pk;
        }
    }
    wave_lds_fence();

    const int lr = lane & 15, lg = lane >> 4;
    floatx4 acc[8];
#pragma unroll
    for (int nt = 0; nt < 8; ++nt) {
        const float4 bv = *(const float4*)&bias[nt * 16 + lg * 4];
        acc[nt] = (floatx4){bv.x, bv.y, bv.z, bv.w};
    }
    const unsigned short* brow = &B[wv * 16 + lr][0];
#pragma unroll 2
    for (int kb = 0; kb < 4; ++kb) {
        const short8 mf = *(const short8*)(brow + kb * 32 + lg * 8);
#pragma unroll
        for (int nt = 0; nt < 8; ++nt) {
            const short8 wf = *(const short8*)(Wpm + ((size_t)(nt * 4 + kb) * 64 + lane) * 8);
            acc[nt] = __builtin_amdgcn_mfma_f32_16x16x32_bf16(wf, mf, acc[nt], 0, 0, 0);
        }
    }
    const int node = n0 + wv * 16 + lr;
    if (node < N) {
        unsigned short* drow = &h_node_bf[(size_t)node * 128];
#pragma unroll
        for (int nt = 0; nt < 8; ++nt) {
            float x0 = silu_f(acc[nt][0]), x1 = silu_f(acc[nt][1]);
            float x2 = silu_f(acc[nt][2]), x3 = silu_f(acc[nt][3]);
            unsigned short* p = drow + nt * 16 + lg * 4;
            const uint2 d = *(const uint2*)p;
            x0 += bf2f((unsigned short)(d.x & 0xFFFF));
            x1 += bf2f((unsigned short)(d.x >> 16));
            x2 += bf2f((unsigned short)(d.y & 0xFFFF));
            x3 += bf2f((unsigned short)(d.y >> 16));
            uint2 o;
            o.x = f2bf_pk(x0, x1);
            o.y = f2bf_pk(x2, x3);
            *(uint2*)p = o;
        }
    }
}

// ---------------------------------------------------------------------------
// MFMA row GEMM (atom embedding): dst = gather(src)[z] @ W + b, bf16 out.
// ---------------------------------------------------------------------------
__global__ __launch_bounds__(256, 4) void atom_gemm_mfma_kernel(
    const float* __restrict__ src, const int* __restrict__ gidx,
    const unsigned short* __restrict__ Wpm, const float* __restrict__ bias,
    unsigned short* __restrict__ dst, int N)
{
    __shared__ __align__(16) unsigned short B[64][136];
    const int tid  = threadIdx.x;
    const int lane = tid & 63;
    const int wv   = tid >> 6;
    const int n0   = blockIdx.x * 64;

    {
        const int t = tid >> 2, q = tid & 3;
        const int node = n0 + t;
        const float* srow = src;
        if (node < N) srow = &src[(size_t)gidx[node] * 128];
#pragma unroll
        for (int i = 0; i < 4; ++i) {
            const int k8 = (q + 4 * i) << 3;
            uint4 pk = make_uint4(0, 0, 0, 0);
            if (node < N) {
                const float4 f0 = *(const float4*)(srow + k8);
                const float4 f1 = *(const float4*)(srow + k8 + 4);
                pk.x = f2bf_pk(f0.x, f0.y);
                pk.y = f2bf_pk(f0.z, f0.w);
                pk.z = f2bf_pk(f1.x, f1.y);
                pk.w = f2bf_pk(f1.z, f1.w);
            }
            *(uint4*)&B[t][k8] = pk;
        }
    }
    wave_lds_fence();

    const int lr = lane & 15, lg = lane >> 4;
    floatx4 acc[8];
#pragma unroll
    for (int nt = 0; nt < 8; ++nt) {
        const float4 bv = *(const float4*)&bias[nt * 16 + lg * 4];
        acc[nt] = (floatx4){bv.x, bv.y, bv.z, bv.w};
    }
    const unsigned short* brow = &B[wv * 16 + lr][0];
#pragma unroll 2
    for (int kb = 0; kb < 4; ++kb) {
        const short8 mf = *(const short8*)(brow + kb * 32 + lg * 8);
#pragma unroll
        for (int nt = 0; nt < 8; ++nt) {
            const short8 wf = *(const short8*)(Wpm + ((size_t)(nt * 4 + kb) * 64 + lane) * 8);
            acc[nt] = __builtin_amdgcn_mfma_f32_16x16x32_bf16(wf, mf, acc[nt], 0, 0, 0);
        }
    }
    const int node = n0 + wv * 16 + lr;
    if (node < N) {
        unsigned short* drow = &dst[(size_t)node * 128];
#pragma unroll
        for (int nt = 0; nt < 8; ++nt) {
            uint2 o;
            o.x = f2bf_pk(acc[nt][0], acc[nt][1]);
            o.y = f2bf_pk(acc[nt][2], acc[nt][3]);
            *(uint2*)(drow + nt * 16 + lg * 4) = o;
        }
    }
}

// ---------------------------------------------------------------------------
// MFMA edge embedding: basis [64,32] bf16 in LDS, one K=32 MFMA pass.
// ---------------------------------------------------------------------------
__global__ __launch_bounds__(256, 4) void edge_embed_mfma_kernel(
    const float* __restrict__ pos, const int* __restrict__ row, const int* __restrict__ col,
    const unsigned short* __restrict__ Wpe, const float* __restrict__ bemb,
    unsigned short* __restrict__ h_edge)
{
    __shared__ __align__(16) unsigned short Bas[64][40];
    const int tid  = threadIdx.x;
    const int lane = tid & 63;
    const int wv   = tid >> 6;
    const int e0   = blockIdx.x * 64;

    {
        const int t = tid >> 2, q = tid & 3;
        const int rr = row[e0 + t], cc = col[e0 + t];
        const float dx = pos[rr * 3 + 0] - pos[cc * 3 + 0];
        const float dy = pos[rr * 3 + 1] - pos[cc * 3 + 1];
        const float dz = pos[rr * 3 + 2] - pos[cc * 3 + 2];
        const float d = sqrtf(dx * dx + dy * dy + dz * dz);
        const float invs = 32.0f / 5.0f;
        float e[8];
#pragma unroll
        for (int j = 0; j < 8; ++j) {
            const float mu = (float)(q * 8 + j) * (5.0f / 31.0f);
            const float tt = (d - mu) * invs;
            e[j] = __expf(-0.5f * tt * tt);
        }
        uint4 pk;
        pk.x = f2bf_pk(e[0], e[1]);
        pk.y = f2bf_pk(e[2], e[3]);
        pk.z = f2bf_pk(e[4], e[5]);
        pk.w = f2bf_pk(e[6], e[7]);
        *(uint4*)&Bas[t][q * 8] = pk;
    }
    wave_lds_fence();

    const int lr = lane & 15, lg = lane >> 4;
    floatx4 acc[8];
#pragma unroll
    for (int nt = 0; nt < 8; ++nt) {
        const float4 bv = *(const float4*)&bemb[nt * 16 + lg * 4];
        acc[nt] = (floatx4){bv.x, bv.y, bv.z, bv.w};
    }
    const short8 mf = *(const short8*)&Bas[wv * 16 + lr][lg * 8];
#pragma unroll
    for (int nt = 0; nt < 8; ++nt) {
        const short8 wf = *(const short8*)(Wpe + ((size_t)nt * 64 + lane) * 8);
        acc[nt] = __builtin_amdgcn_mfma_f32_16x16x32_bf16(wf, mf, acc[nt], 0, 0, 0);
    }
    unsigned short* erow = &h_edge[(size_t)(e0 + wv * 16 + lr) * 128];
#pragma unroll
    for (int nt = 0; nt < 8; ++nt) {
        uint2 o;
        o.x = f2bf_pk(acc[nt][0], acc[nt][1]);
        o.y = f2bf_pk(acc[nt][2], acc[nt][3]);
        *(uint2*)(erow + nt * 16 + lg * 4) = o;
    }
}

// ---------------------------------------------------------------------------
// Graph pooling (bf16 node state) + output head.
// ---------------------------------------------------------------------------
__global__ __launch_bounds__(128) void pool_kernel(
    const unsigned short* __restrict__ h_node_bf, const int* __restrict__ batch,
    float* __restrict__ sums, float* __restrict__ cnt, int N)
{
    __shared__ int bb[256];
    const int tid = threadIdx.x;
    const int n0 = blockIdx.x * 256;
    for (int idx = tid; idx < 256; idx += 128) {
        int n = n0 + idx;
        bb[idx] = (n < N) ? batch[n] : -1;
    }
    __syncthreads();
    int cur = bb[0];
    float run = 0.f, runc = 0.f;
    for (int i = 0; i < 256; ++i) {
        const int b = bb[i];
        if (b < 0) break;
        if (b != cur) {
            atomicAdd(&sums[(size_t)cur * 128 + tid], run);
            if (tid == 0) atomicAdd(&cnt[cur], runc);
            run = 0.f; runc = 0.f; cur = b;
        }
        run += bf2f(h_node_bf[(size_t)(n0 + i) * 128 + tid]);
        runc += 1.f;
    }
    atomicAdd(&sums[(size_t)cur * 128 + tid], run);
    if (tid == 0) atomicAdd(&cnt[cur], runc);
}

__global__ __launch_bounds__(256) void final_kernel(
    const float* __restrict__ sums, const float* __restrict__ cnt,
    const float* __restrict__ out_w, const float* __restrict__ out_b,
    float* __restrict__ out)
{
    const int g = threadIdx.x;
    const float c = fmaxf(cnt[g], 1.0f);
    float acc = 0.f;
    for (int jj = 0; jj < 128; ++jj) acc = fmaf(sums[(size_t)g * 128 + jj], out_w[jj], acc);
    out[g] = acc / c + out_b[0];
}

__global__ void zero_out_kernel(float* out, int n) {
    int i = blockIdx.x * 256 + threadIdx.x;
    if (i < n) out[i] = 0.f;
}

// ---------------------------------------------------------------------------

extern "C" void kernel_launch(void* const* d_in, const int* in_sizes, int n_in,
                              void* d_out, int out_size, void* d_ws, size_t ws_size,
                              hipStream_t stream)
{
    const int*   z          = (const int*)  d_in[0];
    const float* pos        = (const float*)d_in[1];
    const int*   batch      = (const int*)  d_in[2];
    const int*   eidx       = (const int*)  d_in[3];
    const float* atom_table = (const float*)d_in[4];
    const float* atom_w     = (const float*)d_in[5];
    const float* atom_b     = (const float*)d_in[6];
    const float* edge_emb_w = (const float*)d_in[7];
    const float* edge_emb_b = (const float*)d_in[8];
    const float* edge_w0    = (const float*)d_in[9];
    const float* edge_b0    = (const float*)d_in[10];
    const float* edge_w     = (const float*)d_in[11];
    const float* edge_b     = (const float*)d_in[12];
    const float* node_w     = (const float*)d_in[13];
    const float* node_b     = (const float*)d_in[14];
    const float* out_w      = (const float*)d_in[15];
    const float* out_b      = (const float*)d_in[16];
    const int* row = eidx;
    const int* col = eidx + N_EDGES_;

    // ws layout (identical to round 9 — known to fit):
    // agg f32 (now unused, kept for layout stability) | sums | cnt |
    // h_node bf16 | h_edge bf16 | Wp bf16 | hist | cursor | row_s | col_s
    float* aggb = (float*)d_ws;
    float* sums = aggb + (size_t)N_NODES_ * EMB;
    float* cnt  = sums + (size_t)N_GRAPH_ * EMB;
    unsigned short* h_node_bf = (unsigned short*)(cnt + N_GRAPH_);
    unsigned short* h_edge    = h_node_bf + (size_t)N_NODES_ * EMB;
    unsigned short* Wp        = h_edge + (size_t)N_EDGES_ * EMB;
    int* hist   = (int*)(Wp + WP_TOTAL);
    int* cursor = hist + N_NODES_;
    int* row_s  = cursor + N_NODES_;
    int* col_s  = row_s + N_EDGES_;

    const size_t need = ((size_t)(N_NODES_ * EMB + N_GRAPH_ * EMB + N_GRAPH_)) * 4
                      + ((size_t)N_NODES_ * EMB + (size_t)N_EDGES_ * EMB + (size_t)WP_TOTAL) * 2
                      + ((size_t)N_NODES_ * 2 + (size_t)N_EDGES_ * 2) * 4;

    if (ws_size < need) {
        zero_out_kernel<<<1, 256, 0, stream>>>((float*)d_out, N_GRAPH_);
        return;
    }

    const int grid_rows64 = (N_NODES_ + 63) / 64;   // 782

    (void)hipMemsetAsync(hist, 0, N_NODES_ * sizeof(int), stream);
    hist_kernel<<<(N_EDGES_ + 255) / 256, 256, 0, stream>>>(row, hist);
    scan_kernel<<<1, 256, 0, stream>>>(hist, cursor);
    scatter_kernel<<<(N_EDGES_ + 255) / 256, 256, 0, stream>>>(row, col, cursor, row_s, col_s);
    // post-scatter: cursor[n] = end offset, hist[n] = degree

    pack_w_kernel<<<256, 256, 0, stream>>>(edge_w0, edge_w, atom_w, node_w, edge_emb_w, Wp);

    atom_gemm_mfma_kernel<<<grid_rows64, 256, 0, stream>>>(
        atom_table, z, Wp + WP_ATOM, atom_b, h_node_bf, N_NODES_);
    edge_embed_mfma_kernel<<<N_EDGES_ / 64, 256, 0, stream>>>(
        pos, row_s, col_s, Wp + WP_EMB, edge_emb_b, h_edge);

    for (int l = 0; l < NLAYER_; ++l) {
        edge_mlp_csr_kernel<<<N_EDGES_ / 64, 256, 0, stream>>>(
            h_node_bf, h_edge, row_s, col_s,
            Wp + (size_t)l * 114688,
            edge_b0 + (size_t)l * 128, edge_b + (size_t)l * 4 * 128);
        node_agg_gemm_kernel<<<grid_rows64, 256, 0, stream>>>(
            h_edge, hist, cursor,
            Wp + WP_NODE0 + (size_t)l * 16384, node_b + (size_t)l * 128,
            h_node_bf, N_NODES_);
    }

    (void)hipMemsetAsync(sums, 0, ((size_t)N_GRAPH_ * EMB + N_GRAPH_) * sizeof(float), stream);
    pool_kernel<<<(N_NODES_ + 255) / 256, 128, 0, stream>>>(h_node_bf, batch, sums, cnt, N_NODES_);
    final_kernel<<<1, 256, 0, stream>>>(sums, cnt, out_w, out_b, (float*)d_out);
}

// Round 11
// 2528.633 us; speedup vs baseline: 1.5551x; 1.0047x over previous
//
#include <hip/hip_runtime.h>

#define EMB      128
#define N_NODES_ 50000
#define N_EDGES_ 800000
#define N_GRAPH_ 256
#define NLAYER_  5

// packed-weight layout offsets (ushort elements)
#define WP_ATOM  573440
#define WP_NODE0 589824
#define WP_EMB   671744
#define WP_TOTAL 675840

typedef short short8 __attribute__((ext_vector_type(8)));
typedef float floatx4 __attribute__((ext_vector_type(4)));

__device__ __forceinline__ float silu_f(float x) {
    return __fdividef(x, 1.0f + __expf(-x));
}
__device__ __forceinline__ float bf2f(unsigned short h) {
    return __uint_as_float(((unsigned)h) << 16);
}
__device__ __forceinline__ unsigned short f2bf(float f) {
    unsigned u = __float_as_uint(f);
    unsigned r = 0x7FFFu + ((u >> 16) & 1u);
    return (unsigned short)((u + r) >> 16);
}

#if defined(__has_builtin)
#if __has_builtin(__builtin_amdgcn_cvt_pk_bf16_f32)
#define HAVE_PK_BF16 1
#endif
#endif
#ifdef HAVE_PK_BF16
typedef __bf16 bf16x2 __attribute__((ext_vector_type(2)));
__device__ __forceinline__ unsigned f2bf_pk(float a, float b) {
    bf16x2 v = __builtin_amdgcn_cvt_pk_bf16_f32(a, b);
    unsigned u;
    __builtin_memcpy(&u, &v, 4);
    return u;
}
#else
__device__ __forceinline__ unsigned f2bf_pk(float a, float b) {
    return (unsigned)f2bf(a) | ((unsigned)f2bf(b) << 16);
}
#endif

// wave-local LDS ordering (validated round 9: correctness held)
__device__ __forceinline__ void wave_lds_fence() {
    __builtin_amdgcn_fence(__ATOMIC_ACQ_REL, "wavefront");
    __builtin_amdgcn_wave_barrier();
}

// ---------------------------------------------------------------------------
// Edge sort by destination row: histogram -> 1-block scan -> atomic scatter.
// After scatter: cursor[n] = END offset of node n's edge run; hist[n] = degree.
// ---------------------------------------------------------------------------
__global__ __launch_bounds__(256) void hist_kernel(
    const int* __restrict__ row, int* __restrict__ hist)
{
    const int e = blockIdx.x * 256 + threadIdx.x;
    if (e < N_EDGES_) atomicAdd(&hist[row[e]], 1);
}

__global__ __launch_bounds__(256) void scan_kernel(
    const int* __restrict__ hist, int* __restrict__ cursor)
{
    __shared__ int ssum[256];
    const int tid = threadIdx.x;
    const int chunk = (N_NODES_ + 255) / 256;
    const int base = tid * chunk;
    int s = 0;
    for (int i = 0; i < chunk; ++i) {
        const int idx = base + i;
        if (idx < N_NODES_) s += hist[idx];
    }
    ssum[tid] = s;
    __syncthreads();
    for (int off = 1; off < 256; off <<= 1) {
        const int t2 = (tid >= off) ? ssum[tid - off] : 0;
        __syncthreads();
        ssum[tid] += t2;
        __syncthreads();
    }
    int run = ssum[tid] - s;
    for (int i = 0; i < chunk; ++i) {
        const int idx = base + i;
        if (idx < N_NODES_) { cursor[idx] = run; run += hist[idx]; }
    }
}

__global__ __launch_bounds__(256) void scatter_kernel(
    const int* __restrict__ row, const int* __restrict__ col,
    int* __restrict__ cursor, int* __restrict__ row_s, int* __restrict__ col_s)
{
    const int e = blockIdx.x * 256 + threadIdx.x;
    if (e >= N_EDGES_) return;
    const int r = row[e];
    const int p = atomicAdd(&cursor[r], 1);
    row_s[p] = r;
    col_s[p] = col[e];
}

// ---------------------------------------------------------------------------
// Weight packing: fp32 [K][128] -> bf16 A-operand (W^T) fragment order.
// 256 blocks: 0..199 edge MLP | 200..207 atom_w | 208..247 node_w | 248..255 emb
// ---------------------------------------------------------------------------
__global__ __launch_bounds__(256) void pack_w_kernel(
    const float* __restrict__ edge_w0, const float* __restrict__ edge_w,
    const float* __restrict__ atom_w, const float* __restrict__ node_w,
    const float* __restrict__ edge_emb_w,
    unsigned short* __restrict__ Wp)
{
    const int bid = blockIdx.x;
    int Kb, t;
    const float* src;
    unsigned short* dst;
    if (bid < 200) {
        const int l = bid / 40, r = bid % 40, s = r / 8;
        t = r % 8;
        Kb = (s == 0) ? 12 : 4;
        src = (s == 0) ? edge_w0 + (size_t)l * 384 * 128
                       : edge_w + ((size_t)l * 4 + (s - 1)) * 128 * 128;
        dst = Wp + (size_t)l * 114688 + ((s == 0) ? 0 : (49152 + (s - 1) * 16384))
            + (size_t)t * Kb * 512;
    } else if (bid < 208) {
        t = bid - 200; Kb = 4; src = atom_w;
        dst = Wp + WP_ATOM + (size_t)t * Kb * 512;
    } else if (bid < 248) {
        const int l = (bid - 208) >> 3; t = (bid - 208) & 7; Kb = 4;
        src = node_w + (size_t)l * 128 * 128;
        dst = Wp + WP_NODE0 + (size_t)l * 16384 + (size_t)t * Kb * 512;
    } else {
        t = bid - 248; Kb = 1; src = edge_emb_w;
        dst = Wp + WP_EMB + (size_t)t * 512;
    }
    const int n = Kb * 512;
    for (int p = threadIdx.x; p < n; p += 256) {
        const int j = p & 7, lane = (p >> 3) & 63, kb = p >> 9;
        const int k  = kb * 32 + ((lane >> 4) << 3) + j;
        const int nn = t * 16 + (lane & 15);
        dst[p] = f2bf(src[(size_t)k * 128 + nn]);
    }
}

// ---------------------------------------------------------------------------
// Sorted-edge MFMA edge MLP (round-8 tile structure: wave = 2 n-tiles x 4
// edge-tiles, 4x weight-frag reuse). Round-11 changes:
//  - ping-pong stage regions: stages 1..4 write a 128-col region DISJOINT
//    from their input -> one barrier/stage instead of two (11 -> 7 total).
//  - staged h_edge chunks carried in registers -> epilogue has zero global
//    loads (residual add uses the register copy).
// ---------------------------------------------------------------------------
__global__ __launch_bounds__(256, 3) void edge_mlp_csr_kernel(
    const unsigned short* __restrict__ h_node_bf, unsigned short* __restrict__ h_edge,
    const int* __restrict__ row_s, const int* __restrict__ col_s,
    const unsigned short* __restrict__ Wp,
    const float* __restrict__ b0, const float* __restrict__ bh)
{
    __shared__ __align__(16) unsigned short A[64][392];   // 50,176 B
    const int tid = threadIdx.x;
    const int e0 = blockIdx.x * 64;

    short8 he_reg[4];   // this thread's staged h_edge chunks (reused in epilogue)

    // staging: thread owns row t = tid>>2, chunks (tid&3)+4i
    {
        const int t = tid >> 2, q = tid & 3;
        const int rg = row_s[e0 + t];
        const int cg = col_s[e0 + t];
        const unsigned short* pe = &h_edge[(size_t)(e0 + t) * 128];
        const unsigned short* pr = &h_node_bf[(size_t)rg * 128];
        const unsigned short* pc = &h_node_bf[(size_t)cg * 128];
#pragma unroll
        for (int i = 0; i < 12; ++i) {
            const int ch = q + 4 * i;              // i<4 <=> ch<16 <=> h_edge part
            const int k8 = ch << 3;
            const unsigned short* src = (ch < 16) ? (pe + k8)
                                      : (ch < 32) ? (pr + (k8 - 128))
                                                  : (pc + (k8 - 256));
            const short8 v = *(const short8*)src;
            if (i < 4) he_reg[i] = v;
            *(short8*)&A[t][k8] = v;
        }
    }
    __syncthreads();

    const int lane = tid & 63;
    const int wv   = tid >> 6;
    const int lr   = lane & 15;
    const int lg   = lane >> 4;
    const int nt0  = 2 * wv, nt1 = nt0 + 1;

    // region schedule: s0 in cols 0..383 -> out 128..255; s1 in 128 -> out 0;
    // s2 in 0 -> out 128; s3 in 128 -> out 0; s4 in 0 -> out 128 (epilogue).
    for (int s = 0; s < 5; ++s) {
        const int Kb   = (s == 0) ? 12 : 4;
        const int inb  = (s == 0) ? 0 : ((s & 1) ? 128 : 0);
        const int outb = (s & 1) ? 0 : 128;
        const unsigned short* __restrict__ Ws =
            Wp + ((s == 0) ? 0 : (49152 + (s - 1) * 16384));
        const float* __restrict__ bias = (s == 0) ? b0 : (bh + (s - 1) * 128);

        const float4 bv0 = *(const float4*)&bias[nt0 * 16 + lg * 4];
        const float4 bv1 = *(const float4*)&bias[nt1 * 16 + lg * 4];
        floatx4 acc0[4], acc1[4];
#pragma unroll
        for (int et = 0; et < 4; ++et) {
            acc0[et] = (floatx4){bv0.x, bv0.y, bv0.z, bv0.w};
            acc1[et] = (floatx4){bv1.x, bv1.y, bv1.z, bv1.w};
        }

        const unsigned short* aptr0 = Ws + ((size_t)(nt0 * Kb) * 64 + lane) * 8;
        const unsigned short* aptr1 = Ws + ((size_t)(nt1 * Kb) * 64 + lane) * 8;
#pragma unroll 2
        for (int kb = 0; kb < Kb; ++kb) {
            const short8 wf0 = *(const short8*)(aptr0 + (size_t)kb * 512);
            const short8 wf1 = *(const short8*)(aptr1 + (size_t)kb * 512);
#pragma unroll
            for (int et = 0; et < 4; ++et) {
                const short8 mf = *(const short8*)&A[et * 16 + lr][inb + kb * 32 + lg * 8];
                acc0[et] = __builtin_amdgcn_mfma_f32_16x16x32_bf16(wf0, mf, acc0[et], 0, 0, 0);
                acc1[et] = __builtin_amdgcn_mfma_f32_16x16x32_bf16(wf1, mf, acc1[et], 0, 0, 0);
            }
        }
        // s==0: output region (128..255) overlaps the input being read by
        // other waves -> protect. s>=1: out region disjoint from in region.
        if (s == 0) __syncthreads();
#pragma unroll
        for (int et = 0; et < 4; ++et) {
            uint2 p0, p1;
            p0.x = f2bf_pk(silu_f(acc0[et][0]), silu_f(acc0[et][1]));
            p0.y = f2bf_pk(silu_f(acc0[et][2]), silu_f(acc0[et][3]));
            p1.x = f2bf_pk(silu_f(acc1[et][0]), silu_f(acc1[et][1]));
            p1.y = f2bf_pk(silu_f(acc1[et][2]), silu_f(acc1[et][3]));
            *(uint2*)&A[et * 16 + lr][outb + nt0 * 16 + lg * 4] = p0;
            *(uint2*)&A[et * 16 + lr][outb + nt1 * 16 + lg * 4] = p1;
        }
        __syncthreads();   // writes visible before next stage's cross-wave reads
    }

    // epilogue: h_edge_new = he_reg + m (stage-4 output in cols 128..255);
    // zero global loads.
    {
        const int t = tid >> 2, q = tid & 3;
        unsigned short* pe = &h_edge[(size_t)(e0 + t) * 128];
#pragma unroll
        for (int i = 0; i < 4; ++i) {
            const int k8 = (q + 4 * i) << 3;
            const short8 mv = *(const short8*)&A[t][128 + k8];
            const short8 ov = he_reg[i];
            float he[8];
#pragma unroll
            for (int j = 0; j < 8; ++j)
                he[j] = bf2f((unsigned short)ov[j]) + bf2f((unsigned short)mv[j]);
            uint4 sv;
            sv.x = f2bf_pk(he[0], he[1]);
            sv.y = f2bf_pk(he[2], he[3]);
            sv.z = f2bf_pk(he[4], he[5]);
            sv.w = f2bf_pk(he[6], he[7]);
            *(uint4*)(pe + k8) = sv;
        }
    }
}

// ---------------------------------------------------------------------------
// Fused CSR segment-sum + MFMA node update:
//   agg[n] = sum of h_edge rows in [cursor[n]-hist[n], cursor[n])  (fp32)
//   h_node[n] += silu(agg @ node_w + node_b)
// ---------------------------------------------------------------------------
__global__ __launch_bounds__(256, 4) void node_agg_gemm_kernel(
    const unsigned short* __restrict__ h_edge,
    const int* __restrict__ hist, const int* __restrict__ cur_end,
    const unsigned short* __restrict__ Wpm, const float* __restrict__ bias,
    unsigned short* __restrict__ h_node_bf, int N)
{
    __shared__ __align__(16) unsigned short B[64][136];
    const int tid  = threadIdx.x;
    const int lane = tid & 63;
    const int wv   = tid >> 6;
    const int n0   = blockIdx.x * 64;

    {
        const int t = tid >> 2, q = tid & 3;
        const int n = n0 + t;
        float a[32];
#pragma unroll
        for (int j = 0; j < 32; ++j) a[j] = 0.f;
        if (n < N) {
            const int e_end = cur_end[n];
            const int e_beg = e_end - hist[n];
            for (int e = e_beg; e < e_end; ++e) {
                const unsigned short* p = &h_edge[(size_t)e * 128 + q * 32];
#pragma unroll
                for (int g = 0; g < 4; ++g) {
                    const short8 v = *(const short8*)(p + g * 8);
#pragma unroll
                    for (int j = 0; j < 8; ++j)
                        a[g * 8 + j] += bf2f((unsigned short)v[j]);
                }
            }
        }
#pragma unroll
        for (int g = 0; g < 4; ++g) {
            uint4 pk;
            pk.x = f2bf_pk(a[g * 8 + 0], a[g * 8 + 1]);
            pk.y = f2bf_pk(a[g * 8 + 2], a[g * 8 + 3]);
            pk.z = f2bf_pk(a[g * 8 + 4], a[g * 8 + 5]);
            pk.w = f2bf_pk(a[g * 8 + 6], a[g * 8 + 7]);
            *(uint4*)&B[t][q * 32 + g * 8] = pk;
        }
    }
    wave_lds_fence();

    const int lr = lane & 15, lg = lane >> 4;
    floatx4 acc[8];
#pragma unroll
    for (int nt = 0; nt < 8; ++nt) {
        const float4 bv = *(const float4*)&bias[nt * 16 + lg * 4];
        acc[nt] = (floatx4){bv.x, bv.y, bv.z, bv.w};
    }
    const unsigned short* brow = &B[wv * 16 + lr][0];
#pragma unroll 2
    for (int kb = 0; kb < 4; ++kb) {
        const short8 mf = *(const short8*)(brow + kb * 32 + lg * 8);
#pragma unroll
        for (int nt = 0; nt < 8; ++nt) {
            const short8 wf = *(const short8*)(Wpm + ((size_t)(nt * 4 + kb) * 64 + lane) * 8);
            acc[nt] = __builtin_amdgcn_mfma_f32_16x16x32_bf16(wf, mf, acc[nt], 0, 0, 0);
        }
    }
    const int node = n0 + wv * 16 + lr;
    if (node < N) {
        unsigned short* drow = &h_node_bf[(size_t)node * 128];
#pragma unroll
        for (int nt = 0; nt < 8; ++nt) {
            float x0 = silu_f(acc[nt][0]), x1 = silu_f(acc[nt][1]);
            float x2 = silu_f(acc[nt][2]), x3 = silu_f(acc[nt][3]);
            unsigned short* p = drow + nt * 16 + lg * 4;
            const uint2 d = *(const uint2*)p;
            x0 += bf2f((unsigned short)(d.x & 0xFFFF));
            x1 += bf2f((unsigned short)(d.x >> 16));
            x2 += bf2f((unsigned short)(d.y & 0xFFFF));
            x3 += bf2f((unsigned short)(d.y >> 16));
            uint2 o;
            o.x = f2bf_pk(x0, x1);
            o.y = f2bf_pk(x2, x3);
            *(uint2*)p = o;
        }
    }
}

// ---------------------------------------------------------------------------
// MFMA row GEMM (atom embedding): dst = gather(src)[z] @ W + b, bf16 out.
// ---------------------------------------------------------------------------
__global__ __launch_bounds__(256, 4) void atom_gemm_mfma_kernel(
    const float* __restrict__ src, const int* __restrict__ gidx,
    const unsigned short* __restrict__ Wpm, const float* __restrict__ bias,
    unsigned short* __restrict__ dst, int N)
{
    __shared__ __align__(16) unsigned short B[64][136];
    const int tid  = threadIdx.x;
    const int lane = tid & 63;
    const int wv   = tid >> 6;
    const int n0   = blockIdx.x * 64;

    {
        const int t = tid >> 2, q = tid & 3;
        const int node = n0 + t;
        const float* srow = src;
        if (node < N) srow = &src[(size_t)gidx[node] * 128];
#pragma unroll
        for (int i = 0; i < 4; ++i) {
            const int k8 = (q + 4 * i) << 3;
            uint4 pk = make_uint4(0, 0, 0, 0);
            if (node < N) {
                const float4 f0 = *(const float4*)(srow + k8);
                const float4 f1 = *(const float4*)(srow + k8 + 4);
                pk.x = f2bf_pk(f0.x, f0.y);
                pk.y = f2bf_pk(f0.z, f0.w);
                pk.z = f2bf_pk(f1.x, f1.y);
                pk.w = f2bf_pk(f1.z, f1.w);
            }
            *(uint4*)&B[t][k8] = pk;
        }
    }
    wave_lds_fence();

    const int lr = lane & 15, lg = lane >> 4;
    floatx4 acc[8];
#pragma unroll
    for (int nt = 0; nt < 8; ++nt) {
        const float4 bv = *(const float4*)&bias[nt * 16 + lg * 4];
        acc[nt] = (floatx4){bv.x, bv.y, bv.z, bv.w};
    }
    const unsigned short* brow = &B[wv * 16 + lr][0];
#pragma unroll 2
    for (int kb = 0; kb < 4; ++kb) {
        const short8 mf = *(const short8*)(brow + kb * 32 + lg * 8);
#pragma unroll
        for (int nt = 0; nt < 8; ++nt) {
            const short8 wf = *(const short8*)(Wpm + ((size_t)(nt * 4 + kb) * 64 + lane) * 8);
            acc[nt] = __builtin_amdgcn_mfma_f32_16x16x32_bf16(wf, mf, acc[nt], 0, 0, 0);
        }
    }
    const int node = n0 + wv * 16 + lr;
    if (node < N) {
        unsigned short* drow = &dst[(size_t)node * 128];
#pragma unroll
        for (int nt = 0; nt < 8; ++nt) {
            uint2 o;
            o.x = f2bf_pk(acc[nt][0], acc[nt][1]);
            o.y = f2bf_pk(acc[nt][2], acc[nt][3]);
            *(uint2*)(drow + nt * 16 + lg * 4) = o;
        }
    }
}

// ---------------------------------------------------------------------------
// MFMA edge embedding: basis [64,32] bf16 in LDS, one K=32 MFMA pass.
// ---------------------------------------------------------------------------
__global__ __launch_bounds__(256, 4) void edge_embed_mfma_kernel(
    const float* __restrict__ pos, const int* __restrict__ row, const int* __restrict__ col,
    const unsigned short* __restrict__ Wpe, const float* __restrict__ bemb,
    unsigned short* __restrict__ h_edge)
{
    __shared__ __align__(16) unsigned short Bas[64][40];
    const int tid  = threadIdx.x;
    const int lane = tid & 63;
    const int wv   = tid >> 6;
    const int e0   = blockIdx.x * 64;

    {
        const int t = tid >> 2, q = tid & 3;
        const int rr = row[e0 + t], cc = col[e0 + t];
        const float dx = pos[rr * 3 + 0] - pos[cc * 3 + 0];
        const float dy = pos[rr * 3 + 1] - pos[cc * 3 + 1];
        const float dz = pos[rr * 3 + 2] - pos[cc * 3 + 2];
        const float d = sqrtf(dx * dx + dy * dy + dz * dz);
        const float invs = 32.0f / 5.0f;
        float e[8];
#pragma unroll
        for (int j = 0; j < 8; ++j) {
            const float mu = (float)(q * 8 + j) * (5.0f / 31.0f);
            const float tt = (d - mu) * invs;
            e[j] = __expf(-0.5f * tt * tt);
        }
        uint4 pk;
        pk.x = f2bf_pk(e[0], e[1]);
        pk.y = f2bf_pk(e[2], e[3]);
        pk.z = f2bf_pk(e[4], e[5]);
        pk.w = f2bf_pk(e[6], e[7]);
        *(uint4*)&Bas[t][q * 8] = pk;
    }
    wave_lds_fence();

    const int lr = lane & 15, lg = lane >> 4;
    floatx4 acc[8];
#pragma unroll
    for (int nt = 0; nt < 8; ++nt) {
        const float4 bv = *(const float4*)&bemb[nt * 16 + lg * 4];
        acc[nt] = (floatx4){bv.x, bv.y, bv.z, bv.w};
    }
    const short8 mf = *(const short8*)&Bas[wv * 16 + lr][lg * 8];
#pragma unroll
    for (int nt = 0; nt < 8; ++nt) {
        const short8 wf = *(const short8*)(Wpe + ((size_t)nt * 64 + lane) * 8);
        acc[nt] = __builtin_amdgcn_mfma_f32_16x16x32_bf16(wf, mf, acc[nt], 0, 0, 0);
    }
    unsigned short* erow = &h_edge[(size_t)(e0 + wv * 16 + lr) * 128];
#pragma unroll
    for (int nt = 0; nt < 8; ++nt) {
        uint2 o;
        o.x = f2bf_pk(acc[nt][0], acc[nt][1]);
        o.y = f2bf_pk(acc[nt][2], acc[nt][3]);
        *(uint2*)(erow + nt * 16 + lg * 4) = o;
    }
}

// ---------------------------------------------------------------------------
// Graph pooling (bf16 node state) + output head.
// ---------------------------------------------------------------------------
__global__ __launch_bounds__(128) void pool_kernel(
    const unsigned short* __restrict__ h_node_bf, const int* __restrict__ batch,
    float* __restrict__ sums, float* __restrict__ cnt, int N)
{
    __shared__ int bb[256];
    const int tid = threadIdx.x;
    const int n0 = blockIdx.x * 256;
    for (int idx = tid; idx < 256; idx += 128) {
        int n = n0 + idx;
        bb[idx] = (n < N) ? batch[n] : -1;
    }
    __syncthreads();
    int cur = bb[0];
    float run = 0.f, runc = 0.f;
    for (int i = 0; i < 256; ++i) {
        const int b = bb[i];
        if (b < 0) break;
        if (b != cur) {
            atomicAdd(&sums[(size_t)cur * 128 + tid], run);
            if (tid == 0) atomicAdd(&cnt[cur], runc);
            run = 0.f; runc = 0.f; cur = b;
        }
        run += bf2f(h_node_bf[(size_t)(n0 + i) * 128 + tid]);
        runc += 1.f;
    }
    atomicAdd(&sums[(size_t)cur * 128 + tid], run);
    if (tid == 0) atomicAdd(&cnt[cur], runc);
}

__global__ __launch_bounds__(256) void final_kernel(
    const float* __restrict__ sums, const float* __restrict__ cnt,
    const float* __restrict__ out_w, const float* __restrict__ out_b,
    float* __restrict__ out)
{
    const int g = threadIdx.x;
    const float c = fmaxf(cnt[g], 1.0f);
    float acc = 0.f;
    for (int jj = 0; jj < 128; ++jj) acc = fmaf(sums[(size_t)g * 128 + jj], out_w[jj], acc);
    out[g] = acc / c + out_b[0];
}

__global__ void zero_out_kernel(float* out, int n) {
    int i = blockIdx.x * 256 + threadIdx.x;
    if (i < n) out[i] = 0.f;
}

// ---------------------------------------------------------------------------

extern "C" void kernel_launch(void* const* d_in, const int* in_sizes, int n_in,
                              void* d_out, int out_size, void* d_ws, size_t ws_size,
                              hipStream_t stream)
{
    const int*   z          = (const int*)  d_in[0];
    const float* pos        = (const float*)d_in[1];
    const int*   batch      = (const int*)  d_in[2];
    const int*   eidx       = (const int*)  d_in[3];
    const float* atom_table = (const float*)d_in[4];
    const float* atom_w     = (const float*)d_in[5];
    const float* atom_b     = (const float*)d_in[6];
    const float* edge_emb_w = (const float*)d_in[7];
    const float* edge_emb_b = (const float*)d_in[8];
    const float* edge_w0    = (const float*)d_in[9];
    const float* edge_b0    = (const float*)d_in[10];
    const float* edge_w     = (const float*)d_in[11];
    const float* edge_b     = (const float*)d_in[12];
    const float* node_w     = (const float*)d_in[13];
    const float* node_b     = (const float*)d_in[14];
    const float* out_w      = (const float*)d_in[15];
    const float* out_b      = (const float*)d_in[16];
    const int* row = eidx;
    const int* col = eidx + N_EDGES_;

    // ws layout (identical to round 10 — known to fit)
    float* aggb = (float*)d_ws;
    float* sums = aggb + (size_t)N_NODES_ * EMB;
    float* cnt  = sums + (size_t)N_GRAPH_ * EMB;
    unsigned short* h_node_bf = (unsigned short*)(cnt + N_GRAPH_);
    unsigned short* h_edge    = h_node_bf + (size_t)N_NODES_ * EMB;
    unsigned short* Wp        = h_edge + (size_t)N_EDGES_ * EMB;
    int* hist   = (int*)(Wp + WP_TOTAL);
    int* cursor = hist + N_NODES_;
    int* row_s  = cursor + N_NODES_;
    int* col_s  = row_s + N_EDGES_;

    const size_t need = ((size_t)(N_NODES_ * EMB + N_GRAPH_ * EMB + N_GRAPH_)) * 4
                      + ((size_t)N_NODES_ * EMB + (size_t)N_EDGES_ * EMB + (size_t)WP_TOTAL) * 2
                      + ((size_t)N_NODES_ * 2 + (size_t)N_EDGES_ * 2) * 4;

    if (ws_size < need) {
        zero_out_kernel<<<1, 256, 0, stream>>>((float*)d_out, N_GRAPH_);
        return;
    }

    const int grid_rows64 = (N_NODES_ + 63) / 64;   // 782

    (void)hipMemsetAsync(hist, 0, N_NODES_ * sizeof(int), stream);
    hist_kernel<<<(N_EDGES_ + 255) / 256, 256, 0, stream>>>(row, hist);
    scan_kernel<<<1, 256, 0, stream>>>(hist, cursor);
    scatter_kernel<<<(N_EDGES_ + 255) / 256, 256, 0, stream>>>(row, col, cursor, row_s, col_s);
    // post-scatter: cursor[n] = end offset, hist[n] = degree

    pack_w_kernel<<<256, 256, 0, stream>>>(edge_w0, edge_w, atom_w, node_w, edge_emb_w, Wp);

    atom_gemm_mfma_kernel<<<grid_rows64, 256, 0, stream>>>(
        atom_table, z, Wp + WP_ATOM, atom_b, h_node_bf, N_NODES_);
    edge_embed_mfma_kernel<<<N_EDGES_ / 64, 256, 0, stream>>>(
        pos, row_s, col_s, Wp + WP_EMB, edge_emb_b, h_edge);

    for (int l = 0; l < NLAYER_; ++l) {
        edge_mlp_csr_kernel<<<N_EDGES_ / 64, 256, 0, stream>>>(
            h_node_bf, h_edge, row_s, col_s,
            Wp + (size_t)l * 114688,
            edge_b0 + (size_t)l * 128, edge_b + (size_t)l * 4 * 128);
        node_agg_gemm_kernel<<<grid_rows64, 256, 0, stream>>>(
            h_edge, hist, cursor,
            Wp + WP_NODE0 + (size_t)l * 16384, node_b + (size_t)l * 128,
            h_node_bf, N_NODES_);
    }

    (void)hipMemsetAsync(sums, 0, ((size_t)N_GRAPH_ * EMB + N_GRAPH_) * sizeof(float), stream);
    pool_kernel<<<(N_NODES_ + 255) / 256, 128, 0, stream>>>(h_node_bf, batch, sums, cnt, N_NODES_);
    final_kernel<<<1, 256, 0, stream>>>(sums, cnt, out_w, out_b, (float*)d_out);
}